// Round 1
// baseline (2568.662 us; speedup 1.0000x reference)
//
#include <hip/hip_runtime.h>

#define N_ATOMS 50000
#define NEIGH   12
#define NEDGE   (N_ATOMS * NEIGH)
#define NCRYS   500

constexpr int BM = 32;   // rows per block
constexpr int KT = 16;   // K tile

// OUT[N x 256] = A[N x K] @ [Wl; Wr]^T   (cols 0-127 = Wl proj, 128-255 = Wr proj)
// MODE 0: A is dense N x K global
// MODE 1: A is bond_fea N x 12, GBF-expanded on the fly (K=480, 40 filters)
// MODE 2: A is angle_fea N x 144, GBF-expanded on the fly (K=1152, 8 filters)
template <int MODE, int K>
__global__ __launch_bounds__(256) void gemm_kernel(
    const float* __restrict__ A, const float* __restrict__ Wl,
    const float* __restrict__ Wr, float* __restrict__ outp, int n) {
  __shared__ float At[KT][36];    // padded: stride 36 -> 2-way max on write, aligned float4 reads
  __shared__ float Wt[KT][256];
  const int tid = threadIdx.x;
  const int row0 = blockIdx.x * BM;
  const int tc = tid & 63;   // 64 col groups x 4 cols
  const int tr = tid >> 6;   // 4 row groups x 8 rows
  const int kq = tid & 3;
  const int cb = tid >> 2;

  float acc[8][4];
#pragma unroll
  for (int i = 0; i < 8; ++i)
#pragma unroll
    for (int j = 0; j < 4; ++j) acc[i][j] = 0.f;

  for (int k0 = 0; k0 < K; k0 += KT) {
    __syncthreads();
    // ---- A tile (compute GBF on the fly for MODE 1/2) ----
#pragma unroll
    for (int e = tid; e < KT * BM; e += 256) {
      int k = e & (KT - 1);
      int r = e >> 4;
      int row = row0 + r;
      if (row >= n) row = n - 1;
      float val;
      if (MODE == 0) {
        val = A[(size_t)row * K + k0 + k];
      } else if (MODE == 1) {
        int kg = k0 + k;
        int j = kg / 40, kk = kg % 40;
        float d = A[row * 12 + j];
        float f = kk * (8.0f / 39.0f);
        float t = d - f;
        val = __expf(-t * t * 25.0f);  // gamma^2 = (8/40)^2 = 0.04
      } else {
        int kg = k0 + k;
        int j = kg >> 3, kk = kg & 7;
        float d = A[row * 144 + j];
        float f = -1.0f + kk * (2.0f / 7.0f);
        float t = d - f;
        val = __expf(-t * t * 16.0f);  // gamma^2 = (2/8)^2 = 0.0625
      }
      At[k][r] = val;
    }
    // ---- W tile: Wt[k][c] = Wcat[c][k0+k] ----
#pragma unroll
    for (int cpass = 0; cpass < 4; ++cpass) {
      int c = cpass * 64 + cb;
      const float* wrow = (c < 128) ? (Wl + (size_t)c * K) : (Wr + (size_t)(c - 128) * K);
      float4 w = *(const float4*)(wrow + k0 + kq * 4);
      Wt[kq * 4 + 0][c] = w.x;
      Wt[kq * 4 + 1][c] = w.y;
      Wt[kq * 4 + 2][c] = w.z;
      Wt[kq * 4 + 3][c] = w.w;
    }
    __syncthreads();
    // ---- FMA ----
#pragma unroll
    for (int k = 0; k < KT; ++k) {
      float4 b = *(const float4*)&Wt[k][tc * 4];
      const float4* ap = (const float4*)&At[k][tr * 8];
      float4 a0 = ap[0], a1 = ap[1];
      float ar[8] = {a0.x, a0.y, a0.z, a0.w, a1.x, a1.y, a1.z, a1.w};
#pragma unroll
      for (int rr = 0; rr < 8; ++rr) {
        acc[rr][0] += ar[rr] * b.x;
        acc[rr][1] += ar[rr] * b.y;
        acc[rr][2] += ar[rr] * b.z;
        acc[rr][3] += ar[rr] * b.w;
      }
    }
  }
#pragma unroll
  for (int rr = 0; rr < 8; ++rr) {
    int row = row0 + tr * 8 + rr;
    if (row < n) {
      float4 v = make_float4(acc[rr][0], acc[rr][1], acc[rr][2], acc[rr][3]);
      *(float4*)&outp[(size_t)row * 256 + tc * 4] = v;
    }
  }
}

__global__ void count_edges(const int* __restrict__ nbr, float* __restrict__ cnt) {
  int e = blockIdx.x * 256 + threadIdx.x;
  if (e < NEDGE) atomicAdd(&cnt[nbr[e]], 1.0f);
}

// scatter p (= pq cols 0..127) into acc[dst]
__global__ void scatter_kernel(const float* __restrict__ pq, const int* __restrict__ nbr,
                               float* __restrict__ acc) {
  int idx = blockIdx.x * 256 + threadIdx.x;
  int e = idx >> 7;
  int c = idx & 127;
  if (e >= NEDGE) return;
  int i = e / NEIGH;
  int dst = nbr[e];
  atomicAdd(&acc[(size_t)dst * 128 + c], pq[(size_t)i * 256 + c]);
}

// x = relu(acc/max(cnt,1) + bias + q)   where q = pq cols 128..255
__global__ void finalize_kernel(const float* __restrict__ acc, const float* __restrict__ cnt,
                                const float* __restrict__ pq, const float* __restrict__ bias,
                                float* __restrict__ x) {
  int idx = blockIdx.x * 256 + threadIdx.x;
  if (idx >= N_ATOMS * 128) return;
  int i = idx >> 7, c = idx & 127;
  float cc = fmaxf(cnt[i], 1.0f);
  float v = acc[idx] / cc + bias[c] + pq[(size_t)i * 256 + 128 + c];
  x[idx] = fmaxf(v, 0.0f);
}

__global__ void pool_kernel(const float* __restrict__ xb, const float* __restrict__ xa,
                            const int* __restrict__ crys, float* __restrict__ pooled) {
  int cry = blockIdx.x;
  int c = threadIdx.x;  // 256
  int s = crys[cry * 2], e = crys[cry * 2 + 1];
  const float* src = (c < 128) ? xb : xa;
  int ch = c & 127;
  float sum = 0.f;
  for (int r = s; r < e; ++r) sum += src[(size_t)r * 128 + ch];
  float n = fmaxf((float)(e - s), 1.0f);
  pooled[cry * 256 + c] = sum / n;
}

__global__ void mlp_kernel(const float* __restrict__ in, const float* __restrict__ W,
                           const float* __restrict__ b, float* __restrict__ outp) {
  __shared__ float xrow[256];
  int row = blockIdx.x, c = threadIdx.x;
  xrow[c] = in[row * 256 + c];
  __syncthreads();
  const float* wr = W + (size_t)c * 256;
  float s = b[c];
#pragma unroll 8
  for (int k = 0; k < 256; k += 4) {
    float4 w = *(const float4*)&wr[k];
    s += xrow[k] * w.x + xrow[k + 1] * w.y + xrow[k + 2] * w.z + xrow[k + 3] * w.w;
  }
  outp[row * 256 + c] = s;
}

__global__ void fc_kernel(const float* __restrict__ in, const float* __restrict__ W,
                          const float* __restrict__ b, float* __restrict__ outp) {
  int idx = blockIdx.x * 64 + threadIdx.x;
  if (idx >= NCRYS * 2) return;
  int row = idx >> 1, cls = idx & 1;
  float s = b[cls];
  const float* wr = W + cls * 256;
  for (int k = 0; k < 256; ++k) s += in[row * 256 + k] * wr[k];
  outp[idx] = s;
}

extern "C" void kernel_launch(void* const* d_in, const int* in_sizes, int n_in,
                              void* d_out, int out_size, void* d_ws, size_t ws_size,
                              hipStream_t stream) {
  const float* bond  = (const float*)d_in[0];
  const float* angle = (const float*)d_in[1];
  const int*   nbr   = (const int*)d_in[3];
  const int*   crys  = (const int*)d_in[4];
  const float* Wl_b1 = (const float*)d_in[5];
  const float* Wr_b1 = (const float*)d_in[6];
  const float* b_b1  = (const float*)d_in[7];
  const float* Wl_a1 = (const float*)d_in[8];
  const float* Wr_a1 = (const float*)d_in[9];
  const float* b_a1  = (const float*)d_in[10];
  const float* Wl_b  = (const float*)d_in[11];
  const float* Wr_b  = (const float*)d_in[12];
  const float* b_b   = (const float*)d_in[13];
  const float* Wl_a  = (const float*)d_in[14];
  const float* Wr_a  = (const float*)d_in[15];
  const float* b_a   = (const float*)d_in[16];
  const float* W_mlp = (const float*)d_in[17];
  const float* b_mlp = (const float*)d_in[18];
  const float* W_fc  = (const float*)d_in[19];
  const float* b_fc  = (const float*)d_in[20];
  float* outp = (float*)d_out;

  float* ws = (float*)d_ws;
  float* xb     = ws;                               // N*128
  float* xa     = xb + (size_t)N_ATOMS * 128;       // N*128
  float* pq     = xa + (size_t)N_ATOMS * 128;       // N*256
  float* acc    = pq + (size_t)N_ATOMS * 256;       // N*128
  float* cnt    = acc + (size_t)N_ATOMS * 128;      // N
  float* pooled = cnt + N_ATOMS;                    // 500*256
  float* tmp    = pooled + NCRYS * 256;             // 500*256

  const int GEMM_GRID = (N_ATOMS + BM - 1) / BM;  // 1563
  const int SCAT_GRID = NEDGE / 2;                // 300000 (2 edges/block)
  const int FIN_GRID  = (N_ATOMS * 128 + 255) / 256;

  hipMemsetAsync(cnt, 0, N_ATOMS * sizeof(float), stream);
  count_edges<<<(NEDGE + 255) / 256, 256, 0, stream>>>(nbr, cnt);

  // ---- bond path ----
  gemm_kernel<1, 480><<<GEMM_GRID, 256, 0, stream>>>(bond, Wl_b1, Wr_b1, pq, N_ATOMS);
  hipMemsetAsync(acc, 0, (size_t)N_ATOMS * 128 * sizeof(float), stream);
  scatter_kernel<<<SCAT_GRID, 256, 0, stream>>>(pq, nbr, acc);
  finalize_kernel<<<FIN_GRID, 256, 0, stream>>>(acc, cnt, pq, b_b1, xb);
  for (int l = 0; l < 2; ++l) {
    gemm_kernel<0, 128><<<GEMM_GRID, 256, 0, stream>>>(xb, Wl_b + (size_t)l * 128 * 128,
                                                       Wr_b + (size_t)l * 128 * 128, pq, N_ATOMS);
    hipMemsetAsync(acc, 0, (size_t)N_ATOMS * 128 * sizeof(float), stream);
    scatter_kernel<<<SCAT_GRID, 256, 0, stream>>>(pq, nbr, acc);
    finalize_kernel<<<FIN_GRID, 256, 0, stream>>>(acc, cnt, pq, b_b + l * 128, xb);
  }

  // ---- angle path ----
  gemm_kernel<2, 1152><<<GEMM_GRID, 256, 0, stream>>>(angle, Wl_a1, Wr_a1, pq, N_ATOMS);
  hipMemsetAsync(acc, 0, (size_t)N_ATOMS * 128 * sizeof(float), stream);
  scatter_kernel<<<SCAT_GRID, 256, 0, stream>>>(pq, nbr, acc);
  finalize_kernel<<<FIN_GRID, 256, 0, stream>>>(acc, cnt, pq, b_a1, xa);
  for (int l = 0; l < 2; ++l) {
    gemm_kernel<0, 128><<<GEMM_GRID, 256, 0, stream>>>(xa, Wl_a + (size_t)l * 128 * 128,
                                                       Wr_a + (size_t)l * 128 * 128, pq, N_ATOMS);
    hipMemsetAsync(acc, 0, (size_t)N_ATOMS * 128 * sizeof(float), stream);
    scatter_kernel<<<SCAT_GRID, 256, 0, stream>>>(pq, nbr, acc);
    finalize_kernel<<<FIN_GRID, 256, 0, stream>>>(acc, cnt, pq, b_a + l * 128, xa);
  }

  // ---- head ----
  pool_kernel<<<NCRYS, 256, 0, stream>>>(xb, xa, crys, pooled);
  mlp_kernel<<<NCRYS, 256, 0, stream>>>(pooled, W_mlp, b_mlp, tmp);
  mlp_kernel<<<NCRYS, 256, 0, stream>>>(tmp, W_mlp + 256 * 256, b_mlp + 256, pooled);
  fc_kernel<<<(NCRYS * 2 + 63) / 64, 64, 0, stream>>>(pooled, W_fc, b_fc, outp);
}

// Round 2
// 981.013 us; speedup vs baseline: 2.6184x; 2.6184x over previous
//
#include <hip/hip_runtime.h>

typedef _Float16 f16;
typedef _Float16 f16x8 __attribute__((ext_vector_type(8)));
typedef float f32x4 __attribute__((ext_vector_type(4)));

#define N_ATOMS 50000
#define NEIGH   12
#define NEDGE   (N_ATOMS * NEIGH)
#define NCRYS   500
#define NBLK    196  // ceil(50000/256)

__device__ __forceinline__ void gld_lds16(const void* g, void* l) {
  __builtin_amdgcn_global_load_lds(
      (const __attribute__((address_space(1))) unsigned int*)g,
      (__attribute__((address_space(3))) unsigned int*)l, 16, 0, 0);
}

// C[N x 256] = A[N x K] @ Wcat^T, fp16 in / fp16 out, fp32 accum.
// Wcat: fp16 [256][K] (rows 0-127 = Wl, 128-255 = Wr).
// MODE 0: Asrc = fp16 [N][K].  MODE 1: bond fp32 [N][12], GBF K=480.
// MODE 2: angle fp32 [N][144], GBF K=1152.
template <int MODE, int K>
__global__ __launch_bounds__(512) void gemm16(
    const void* __restrict__ Asrc, const f16* __restrict__ Wcat,
    f16* __restrict__ outp, int n) {
  __shared__ __align__(16) f16 As[2][4][128][8];  // [buf][kblk][row][8]
  __shared__ __align__(16) f16 Bs[2][4][256][8];  // [buf][kblk][col][8]
  const int tid = threadIdx.x;
  const int lane = tid & 63;
  const int wid = tid >> 6;
  const int wr = wid >> 2;  // 0..1  (row offset *64)
  const int wc = wid & 3;   // 0..3  (col offset *64)
  const int row0 = blockIdx.x * 128;

  const int sArow = tid & 127;
  const int sAkb = tid >> 7;  // 0..3
  const int sBcol = tid & 255;
  const int sBkb = tid >> 8;  // 0..1 (+2 on pass 1)

  int arow = row0 + sArow;
  if (arow >= n) arow = n - 1;

  f32x4 acc[4][4];
#pragma unroll
  for (int m = 0; m < 4; ++m)
#pragma unroll
    for (int q = 0; q < 4; ++q) acc[m][q] = (f32x4)0.f;

  auto stage = [&](int buf, int k0) {
#pragma unroll
    for (int p = 0; p < 2; ++p) {
      int kb = sBkb + 2 * p;
      gld_lds16(Wcat + (size_t)sBcol * K + k0 + kb * 8, &Bs[buf][kb][sBcol][0]);
    }
    if constexpr (MODE == 0) {
      gld_lds16((const f16*)Asrc + (size_t)arow * K + k0 + sAkb * 8,
                &As[buf][sAkb][sArow][0]);
    } else {
      f16 v[8];
#pragma unroll
      for (int j = 0; j < 8; ++j) {
        int kg = k0 + sAkb * 8 + j;
        float d, f, g2i;
        if constexpr (MODE == 1) {
          int jn = kg / 40;
          int kk = kg - jn * 40;
          d = ((const float*)Asrc)[arow * NEIGH + jn];
          f = kk * (8.0f / 39.0f);
          g2i = 25.0f;  // 1/gamma^2, gamma = 8/40
        } else {
          int jn = kg >> 3;
          int kk = kg & 7;
          d = ((const float*)Asrc)[arow * 144 + jn];
          f = -1.0f + kk * (2.0f / 7.0f);
          g2i = 16.0f;  // gamma = 2/8
        }
        float t = d - f;
        v[j] = (f16)__expf(-t * t * g2i);
      }
      *(f16x8*)&As[buf][sAkb][sArow][0] = *(const f16x8*)v;
    }
  };

  constexpr int NT = K / 32;
  stage(0, 0);
  __syncthreads();
  int buf = 0;
  for (int t = 0; t < NT; ++t) {
    if (t + 1 < NT) stage(buf ^ 1, (t + 1) * 32);
    const int kb = lane >> 4;
    const int r16 = lane & 15;
    f16x8 a[4], b[4];
#pragma unroll
    for (int m = 0; m < 4; ++m)
      a[m] = *(const f16x8*)&As[buf][kb][wr * 64 + m * 16 + r16][0];
#pragma unroll
    for (int q = 0; q < 4; ++q)
      b[q] = *(const f16x8*)&Bs[buf][kb][wc * 64 + q * 16 + r16][0];
#pragma unroll
    for (int m = 0; m < 4; ++m)
#pragma unroll
      for (int q = 0; q < 4; ++q)
        acc[m][q] =
            __builtin_amdgcn_mfma_f32_16x16x32_f16(a[m], b[q], acc[m][q], 0, 0, 0);
    __syncthreads();
    buf ^= 1;
  }

  const int crow = (lane >> 4) * 4;
  const int ccol = lane & 15;
#pragma unroll
  for (int m = 0; m < 4; ++m) {
#pragma unroll
    for (int r = 0; r < 4; ++r) {
      int row = row0 + wr * 64 + m * 16 + crow + r;
      if (row < n) {
#pragma unroll
        for (int q = 0; q < 4; ++q) {
          int col = wc * 64 + q * 16 + ccol;
          outp[(size_t)row * 256 + col] = (f16)acc[m][q][r];
        }
      }
    }
  }
}

__global__ void cvtW(const float* __restrict__ Wl, const float* __restrict__ Wr,
                     f16* __restrict__ outp, int K) {
  int c = blockIdx.y;
  int k = blockIdx.x * 256 + threadIdx.x;
  if (k < K)
    outp[(size_t)c * K + k] =
        (f16)((c < 128) ? Wl[(size_t)c * K + k] : Wr[(size_t)(c - 128) * K + k]);
}

__global__ void k_count(const int* __restrict__ nbr, int* __restrict__ deg) {
  int e = blockIdx.x * 256 + threadIdx.x;
  if (e < NEDGE) atomicAdd(&deg[nbr[e]], 1);
}

__global__ void k_scan1(const int* __restrict__ deg, int* __restrict__ rowptr,
                        int* __restrict__ bsum) {
  __shared__ int s[256];
  int t = threadIdx.x, i = blockIdx.x * 256 + t;
  int v = (i < N_ATOMS) ? deg[i] : 0;
  s[t] = v;
  __syncthreads();
  for (int off = 1; off < 256; off <<= 1) {
    int x = (t >= off) ? s[t - off] : 0;
    __syncthreads();
    s[t] += x;
    __syncthreads();
  }
  if (i < N_ATOMS) rowptr[i] = s[t] - v;  // local exclusive
  if (t == 255) bsum[blockIdx.x] = s[255];
}

__global__ void k_scan2(int* __restrict__ bsum) {
  __shared__ int s[256];
  int t = threadIdx.x;
  int v = (t < NBLK) ? bsum[t] : 0;
  s[t] = v;
  __syncthreads();
  for (int off = 1; off < 256; off <<= 1) {
    int x = (t >= off) ? s[t - off] : 0;
    __syncthreads();
    s[t] += x;
    __syncthreads();
  }
  if (t < NBLK) bsum[t] = s[t] - v;  // exclusive block offsets
}

__global__ void k_scan3(int* __restrict__ rowptr, const int* __restrict__ bsum) {
  int i = blockIdx.x * 256 + threadIdx.x;
  if (i < N_ATOMS) rowptr[i] += bsum[blockIdx.x];
  if (i == 0) rowptr[N_ATOMS] = NEDGE;
}

__global__ void k_fill(const int* __restrict__ nbr, const int* __restrict__ rowptr,
                       int* __restrict__ cursor, int* __restrict__ eidx) {
  int e = blockIdx.x * 256 + threadIdx.x;
  if (e < NEDGE) {
    int dst = nbr[e];
    int pos = rowptr[dst] + atomicAdd(&cursor[dst], 1);
    eidx[pos] = e / NEIGH;  // src atom
  }
}

// x[i][c] = relu( mean_j pq[eidx[j]][c] + bias[c] + pq[i][128+c] )
__global__ void gather_fin(const f16* __restrict__ pq, const int* __restrict__ rowptr,
                           const int* __restrict__ eidx, const float* __restrict__ bias,
                           f16* __restrict__ x) {
  int idx = blockIdx.x * 256 + threadIdx.x;
  int i = idx >> 7, c = idx & 127;
  int s0 = rowptr[i], s1 = rowptr[i + 1];
  float s = 0.f;
  for (int j = s0; j < s1; ++j) {
    int src = eidx[j];
    s += (float)pq[(size_t)src * 256 + c];
  }
  float dg = fmaxf((float)(s1 - s0), 1.0f);
  float v = s / dg + bias[c] + (float)pq[(size_t)i * 256 + 128 + c];
  x[(size_t)i * 128 + c] = (f16)fmaxf(v, 0.0f);
}

__global__ void pool_kernel(const f16* __restrict__ xb, const f16* __restrict__ xa,
                            const int* __restrict__ crys, float* __restrict__ pooled) {
  int cry = blockIdx.x;
  int c = threadIdx.x;  // 256
  int s = crys[cry * 2], e = crys[cry * 2 + 1];
  const f16* src = (c < 128) ? xb : xa;
  int ch = c & 127;
  float sum = 0.f;
  for (int r = s; r < e; ++r) sum += (float)src[(size_t)r * 128 + ch];
  pooled[cry * 256 + c] = sum / fmaxf((float)(e - s), 1.0f);
}

__global__ void mlp_kernel(const float* __restrict__ in, const float* __restrict__ W,
                           const float* __restrict__ b, float* __restrict__ outp) {
  __shared__ float xrow[256];
  int row = blockIdx.x, c = threadIdx.x;
  xrow[c] = in[row * 256 + c];
  __syncthreads();
  const float* wr = W + (size_t)c * 256;
  float s = b[c];
#pragma unroll 8
  for (int k = 0; k < 256; k += 4) {
    float4 w = *(const float4*)&wr[k];
    s += xrow[k] * w.x + xrow[k + 1] * w.y + xrow[k + 2] * w.z + xrow[k + 3] * w.w;
  }
  outp[row * 256 + c] = s;
}

__global__ void fc_kernel(const float* __restrict__ in, const float* __restrict__ W,
                          const float* __restrict__ b, float* __restrict__ outp) {
  int idx = blockIdx.x * 64 + threadIdx.x;
  if (idx >= NCRYS * 2) return;
  int row = idx >> 1, cls = idx & 1;
  float s = b[cls];
  const float* wrow = W + cls * 256;
  for (int k = 0; k < 256; ++k) s += in[row * 256 + k] * wrow[k];
  outp[idx] = s;
}

extern "C" void kernel_launch(void* const* d_in, const int* in_sizes, int n_in,
                              void* d_out, int out_size, void* d_ws, size_t ws_size,
                              hipStream_t stream) {
  const float* bond  = (const float*)d_in[0];
  const float* angle = (const float*)d_in[1];
  const int*   nbr   = (const int*)d_in[3];
  const int*   crys  = (const int*)d_in[4];
  const float* Wl_b1 = (const float*)d_in[5];
  const float* Wr_b1 = (const float*)d_in[6];
  const float* b_b1  = (const float*)d_in[7];
  const float* Wl_a1 = (const float*)d_in[8];
  const float* Wr_a1 = (const float*)d_in[9];
  const float* b_a1  = (const float*)d_in[10];
  const float* Wl_b  = (const float*)d_in[11];
  const float* Wr_b  = (const float*)d_in[12];
  const float* b_b   = (const float*)d_in[13];
  const float* Wl_a  = (const float*)d_in[14];
  const float* Wr_a  = (const float*)d_in[15];
  const float* b_a   = (const float*)d_in[16];
  const float* W_mlp = (const float*)d_in[17];
  const float* b_mlp = (const float*)d_in[18];
  const float* W_fc  = (const float*)d_in[19];
  const float* b_fc  = (const float*)d_in[20];

  char* w = (char*)d_ws;
  auto alloc = [&](size_t bytes) {
    void* p = (void*)w;
    w += (bytes + 15) & ~(size_t)15;
    return p;
  };
  f16* pq16   = (f16*)alloc((size_t)N_ATOMS * 256 * 2);
  f16* xb16   = (f16*)alloc((size_t)N_ATOMS * 128 * 2);
  f16* xa16   = (f16*)alloc((size_t)N_ATOMS * 128 * 2);
  f16* Wb1c   = (f16*)alloc((size_t)256 * 480 * 2);
  f16* Wa1c   = (f16*)alloc((size_t)256 * 1152 * 2);
  f16* Wsm    = (f16*)alloc((size_t)4 * 256 * 128 * 2);
  int* deg    = (int*)alloc((size_t)N_ATOMS * 4);
  int* cursor = (int*)alloc((size_t)N_ATOMS * 4);
  int* rowptr = (int*)alloc((size_t)(N_ATOMS + 1) * 4);
  int* eidx   = (int*)alloc((size_t)NEDGE * 4);
  int* bsum   = (int*)alloc(256 * 4);
  float* pooled = (float*)alloc((size_t)NCRYS * 256 * 4);
  float* tmp    = (float*)alloc((size_t)NCRYS * 256 * 4);

  // ---- weights -> fp16 Wcat layouts ----
  cvtW<<<dim3(2, 256), 256, 0, stream>>>(Wl_b1, Wr_b1, Wb1c, 480);
  cvtW<<<dim3(5, 256), 256, 0, stream>>>(Wl_a1, Wr_a1, Wa1c, 1152);
  for (int l = 0; l < 2; ++l)
    cvtW<<<dim3(1, 256), 256, 0, stream>>>(Wl_b + (size_t)l * 16384,
                                           Wr_b + (size_t)l * 16384,
                                           Wsm + (size_t)l * 32768, 128);
  for (int l = 0; l < 2; ++l)
    cvtW<<<dim3(1, 256), 256, 0, stream>>>(Wl_a + (size_t)l * 16384,
                                           Wr_a + (size_t)l * 16384,
                                           Wsm + (size_t)(2 + l) * 32768, 128);

  // ---- CSR build (deg & cursor adjacent -> one memset) ----
  hipMemsetAsync(deg, 0, (size_t)2 * N_ATOMS * 4, stream);
  k_count<<<(NEDGE + 255) / 256, 256, 0, stream>>>(nbr, deg);
  k_scan1<<<NBLK, 256, 0, stream>>>(deg, rowptr, bsum);
  k_scan2<<<1, 256, 0, stream>>>(bsum);
  k_scan3<<<NBLK, 256, 0, stream>>>(rowptr, bsum);
  k_fill<<<(NEDGE + 255) / 256, 256, 0, stream>>>(nbr, rowptr, cursor, eidx);

  const int GG = (N_ATOMS + 127) / 128;       // 391
  const int FG = (N_ATOMS * 128) / 256;       // 25000

  // ---- bond path ----
  gemm16<1, 480><<<GG, 512, 0, stream>>>(bond, Wb1c, pq16, N_ATOMS);
  gather_fin<<<FG, 256, 0, stream>>>(pq16, rowptr, eidx, b_b1, xb16);
  for (int l = 0; l < 2; ++l) {
    gemm16<0, 128><<<GG, 512, 0, stream>>>(xb16, Wsm + (size_t)l * 32768, pq16, N_ATOMS);
    gather_fin<<<FG, 256, 0, stream>>>(pq16, rowptr, eidx, b_b + l * 128, xb16);
  }

  // ---- angle path ----
  gemm16<2, 1152><<<GG, 512, 0, stream>>>(angle, Wa1c, pq16, N_ATOMS);
  gather_fin<<<FG, 256, 0, stream>>>(pq16, rowptr, eidx, b_a1, xa16);
  for (int l = 0; l < 2; ++l) {
    gemm16<0, 128><<<GG, 512, 0, stream>>>(xa16, Wsm + (size_t)(2 + l) * 32768, pq16, N_ATOMS);
    gather_fin<<<FG, 256, 0, stream>>>(pq16, rowptr, eidx, b_a + l * 128, xa16);
  }

  // ---- head ----
  pool_kernel<<<NCRYS, 256, 0, stream>>>(xb16, xa16, crys, pooled);
  mlp_kernel<<<NCRYS, 256, 0, stream>>>(pooled, W_mlp, b_mlp, tmp);
  mlp_kernel<<<NCRYS, 256, 0, stream>>>(tmp, W_mlp + 65536, b_mlp + 256, pooled);
  fc_kernel<<<(NCRYS * 2 + 63) / 64, 64, 0, stream>>>(pooled, W_fc, b_fc, (float*)d_out);
}

// Round 3
// 448.966 us; speedup vs baseline: 5.7213x; 2.1851x over previous
//
#include <hip/hip_runtime.h>

typedef _Float16 f16;
typedef _Float16 f16x8 __attribute__((ext_vector_type(8)));
typedef float f32x4 __attribute__((ext_vector_type(4)));

#define N_ATOMS 50000
#define NEIGH   12
#define NEDGE   (N_ATOMS * NEIGH)
#define NCRYS   500
#define NBLK    196  // ceil(50000/256)

__device__ __forceinline__ void gld_lds16(const void* g, void* l) {
  __builtin_amdgcn_global_load_lds(
      (const __attribute__((address_space(1))) unsigned int*)g,
      (__attribute__((address_space(3))) unsigned int*)l, 16, 0, 0);
}

// P[N x 128] = A @ Wl^T, Q[N x 128] = A @ Wr^T. fp16 in/out, fp32 accum.
// Wcat fp16 [256][K] (rows 0-127 = Wl, 128-255 = Wr).
// MODE 0: Asrc fp16 [N][K]. MODE 1: bond fp32 [N][12], GBF K=480.
// MODE 2: angle fp32 [N][144], GBF K=1152.
template <int MODE, int K>
__global__ __launch_bounds__(512) void gemm16(
    const void* __restrict__ Asrc, const f16* __restrict__ Wcat,
    f16* __restrict__ P, f16* __restrict__ Q, int n) {
  __shared__ __align__(16) f16 As[2][4][128][8];  // [buf][kblk][row][8]
  __shared__ __align__(16) f16 Bs[2][4][256][8];  // [buf][kblk][col][8]
  const int tid = threadIdx.x;
  const int lane = tid & 63;
  const int wid = tid >> 6;
  const int wr = wid >> 2;  // 0..1  (row offset *64)
  const int wc = wid & 3;   // 0..3  (col offset *64)
  const int row0 = blockIdx.x * 128;

  const int sArow = tid & 127;
  const int sAkb = tid >> 7;  // 0..3
  const int sBcol = tid & 255;
  const int sBkb = tid >> 8;  // 0..1 (+2 on pass 1)

  int arow = row0 + sArow;
  if (arow >= n) arow = n - 1;

  f32x4 acc[4][4];
#pragma unroll
  for (int m = 0; m < 4; ++m)
#pragma unroll
    for (int q = 0; q < 4; ++q) acc[m][q] = (f32x4)0.f;

  auto stage = [&](int buf, int k0) {
#pragma unroll
    for (int p = 0; p < 2; ++p) {
      int kb = sBkb + 2 * p;
      gld_lds16(Wcat + (size_t)sBcol * K + k0 + kb * 8, &Bs[buf][kb][sBcol][0]);
    }
    if constexpr (MODE == 0) {
      gld_lds16((const f16*)Asrc + (size_t)arow * K + k0 + sAkb * 8,
                &As[buf][sAkb][sArow][0]);
    } else {
      f16 v[8];
#pragma unroll
      for (int j = 0; j < 8; ++j) {
        int kg = k0 + sAkb * 8 + j;
        float d, f, g2i;
        if constexpr (MODE == 1) {
          int jn = kg / 40;
          int kk = kg - jn * 40;
          d = ((const float*)Asrc)[arow * NEIGH + jn];
          f = kk * (8.0f / 39.0f);
          g2i = 25.0f;  // 1/gamma^2, gamma = 8/40
        } else {
          int jn = kg >> 3;
          int kk = kg & 7;
          d = ((const float*)Asrc)[arow * 144 + jn];
          f = -1.0f + kk * (2.0f / 7.0f);
          g2i = 16.0f;  // gamma = 2/8
        }
        float t = d - f;
        v[j] = (f16)__expf(-t * t * g2i);
      }
      *(f16x8*)&As[buf][sAkb][sArow][0] = *(const f16x8*)v;
    }
  };

  constexpr int NT = K / 32;
  stage(0, 0);
  __syncthreads();
  int buf = 0;
  for (int t = 0; t < NT; ++t) {
    if (t + 1 < NT) stage(buf ^ 1, (t + 1) * 32);
    const int kb = lane >> 4;
    const int r16 = lane & 15;
    f16x8 a[4], b[4];
#pragma unroll
    for (int m = 0; m < 4; ++m)
      a[m] = *(const f16x8*)&As[buf][kb][wr * 64 + m * 16 + r16][0];
#pragma unroll
    for (int q = 0; q < 4; ++q)
      b[q] = *(const f16x8*)&Bs[buf][kb][wc * 64 + q * 16 + r16][0];
#pragma unroll
    for (int m = 0; m < 4; ++m)
#pragma unroll
      for (int q = 0; q < 4; ++q)
        acc[m][q] =
            __builtin_amdgcn_mfma_f32_16x16x32_f16(a[m], b[q], acc[m][q], 0, 0, 0);
    __syncthreads();
    buf ^= 1;
  }

  const int crow = (lane >> 4) * 4;
  const int ccol = lane & 15;
  f16* baseo = (wc < 2) ? P : Q;
  const int cbase = (wc & 1) * 64;
#pragma unroll
  for (int m = 0; m < 4; ++m) {
#pragma unroll
    for (int r = 0; r < 4; ++r) {
      int row = row0 + wr * 64 + m * 16 + crow + r;
      if (row < n) {
#pragma unroll
        for (int q = 0; q < 4; ++q) {
          int col = cbase + q * 16 + ccol;
          baseo[(size_t)row * 128 + col] = (f16)acc[m][q][r];
        }
      }
    }
  }
}

__global__ void cvtW(const float* __restrict__ Wl, const float* __restrict__ Wr,
                     f16* __restrict__ outp, int K) {
  int c = blockIdx.y;
  int k = blockIdx.x * 256 + threadIdx.x;
  if (k < K)
    outp[(size_t)c * K + k] =
        (f16)((c < 128) ? Wl[(size_t)c * K + k] : Wr[(size_t)(c - 128) * K + k]);
}

// all four 128x128 layer weights in one launch: out[l][c][k], l=0..3
__global__ void cvtW_small(const float* __restrict__ Wl_b, const float* __restrict__ Wr_b,
                           const float* __restrict__ Wl_a, const float* __restrict__ Wr_a,
                           f16* __restrict__ outp) {
  int idx = blockIdx.x * 256 + threadIdx.x;  // 4*256*128 = 131072
  int l = idx >> 15;
  int c = (idx >> 7) & 255;
  int k = idx & 127;
  const float* Wl = (l < 2) ? Wl_b + (size_t)l * 16384 : Wl_a + (size_t)(l - 2) * 16384;
  const float* Wr = (l < 2) ? Wr_b + (size_t)l * 16384 : Wr_a + (size_t)(l - 2) * 16384;
  float v = (c < 128) ? Wl[(size_t)c * 128 + k] : Wr[(size_t)(c - 128) * 128 + k];
  outp[idx] = (f16)v;
}

__global__ void k_count(const int* __restrict__ nbr, int* __restrict__ deg) {
  int e = blockIdx.x * 256 + threadIdx.x;
  if (e < NEDGE) atomicAdd(&deg[nbr[e]], 1);
}

__global__ void k_scan1(const int* __restrict__ deg, int* __restrict__ rowptr,
                        int* __restrict__ bsum) {
  __shared__ int s[256];
  int t = threadIdx.x, i = blockIdx.x * 256 + t;
  int v = (i < N_ATOMS) ? deg[i] : 0;
  s[t] = v;
  __syncthreads();
  for (int off = 1; off < 256; off <<= 1) {
    int x = (t >= off) ? s[t - off] : 0;
    __syncthreads();
    s[t] += x;
    __syncthreads();
  }
  if (i < N_ATOMS) rowptr[i] = s[t] - v;  // local exclusive
  if (t == 255) bsum[blockIdx.x] = s[255];
}

__global__ void k_scan2(int* __restrict__ bsum) {
  __shared__ int s[256];
  int t = threadIdx.x;
  int v = (t < NBLK) ? bsum[t] : 0;
  s[t] = v;
  __syncthreads();
  for (int off = 1; off < 256; off <<= 1) {
    int x = (t >= off) ? s[t - off] : 0;
    __syncthreads();
    s[t] += x;
    __syncthreads();
  }
  if (t < NBLK) bsum[t] = s[t] - v;  // exclusive block offsets
}

__global__ void k_scan3(int* __restrict__ rowptr, const int* __restrict__ bsum) {
  int i = blockIdx.x * 256 + threadIdx.x;
  if (i < N_ATOMS) rowptr[i] += bsum[blockIdx.x];
  if (i == 0) rowptr[N_ATOMS] = NEDGE;
}

__global__ void k_fill(const int* __restrict__ nbr, const int* __restrict__ rowptr,
                       int* __restrict__ cursor, int* __restrict__ eidx) {
  int e = blockIdx.x * 256 + threadIdx.x;
  if (e < NEDGE) {
    int dst = nbr[e];
    int pos = rowptr[dst] + atomicAdd(&cursor[dst], 1);
    eidx[pos] = e / NEIGH;  // src atom
  }
}

// x[i][c] = relu( mean_j P[eidx[j]][c] + bias[c] + Q[i][c] )
// 16 threads/atom, each owns 8 channels (one f16x8 = 16B load per edge).
__global__ __launch_bounds__(256) void gather_fin(
    const f16* __restrict__ P, const f16* __restrict__ Q,
    const int* __restrict__ rowptr, const int* __restrict__ eidx,
    const float* __restrict__ bias, f16* __restrict__ x) {
  const int t = threadIdx.x;
  const int a = blockIdx.x * 16 + (t >> 4);
  const int g = (t & 15) * 8;  // channel base
  const int s0 = rowptr[a], s1 = rowptr[a + 1];
  float acc[8];
#pragma unroll
  for (int u = 0; u < 8; ++u) acc[u] = 0.f;
  int j = s0;
  for (; j + 4 <= s1; j += 4) {
    int src0 = eidx[j], src1 = eidx[j + 1], src2 = eidx[j + 2], src3 = eidx[j + 3];
    f16x8 v0 = *(const f16x8*)&P[(size_t)src0 * 128 + g];
    f16x8 v1 = *(const f16x8*)&P[(size_t)src1 * 128 + g];
    f16x8 v2 = *(const f16x8*)&P[(size_t)src2 * 128 + g];
    f16x8 v3 = *(const f16x8*)&P[(size_t)src3 * 128 + g];
#pragma unroll
    for (int u = 0; u < 8; ++u)
      acc[u] += ((float)v0[u] + (float)v1[u]) + ((float)v2[u] + (float)v3[u]);
  }
  for (; j < s1; ++j) {
    f16x8 v = *(const f16x8*)&P[(size_t)eidx[j] * 128 + g];
#pragma unroll
    for (int u = 0; u < 8; ++u) acc[u] += (float)v[u];
  }
  f16x8 q = *(const f16x8*)&Q[(size_t)a * 128 + g];
  float4 b0 = *(const float4*)(bias + g);
  float4 b1 = *(const float4*)(bias + g + 4);
  float bb[8] = {b0.x, b0.y, b0.z, b0.w, b1.x, b1.y, b1.z, b1.w};
  float inv = 1.0f / fmaxf((float)(s1 - s0), 1.0f);
  f16 outv[8];
#pragma unroll
  for (int u = 0; u < 8; ++u) {
    float v = acc[u] * inv + bb[u] + (float)q[u];
    outv[u] = (f16)fmaxf(v, 0.0f);
  }
  *(f16x8*)&x[(size_t)a * 128 + g] = *(const f16x8*)outv;
}

// fused: pool -> mlp1 -> mlp2 -> fc   (each crystal independent)
__global__ __launch_bounds__(256) void head_kernel(
    const f16* __restrict__ xb, const f16* __restrict__ xa,
    const int* __restrict__ crys, const float* __restrict__ W_mlp,
    const float* __restrict__ b_mlp, const float* __restrict__ W_fc,
    const float* __restrict__ b_fc, float* __restrict__ outp) {
  __shared__ float sh0[256], sh1[256];
  const int cry = blockIdx.x, c = threadIdx.x;
  const int s = crys[2 * cry], e = crys[2 * cry + 1];
  const f16* src = (c < 128) ? xb : xa;
  const int ch = c & 127;
  float sum = 0.f;
  for (int r = s; r < e; ++r) sum += (float)src[(size_t)r * 128 + ch];
  sh0[c] = sum / fmaxf((float)(e - s), 1.0f);
  __syncthreads();
  {
    const float* wrow = W_mlp + (size_t)c * 256;
    float s2 = b_mlp[c];
#pragma unroll 8
    for (int k = 0; k < 256; k += 4) {
      float4 w = *(const float4*)&wrow[k];
      s2 += sh0[k] * w.x + sh0[k + 1] * w.y + sh0[k + 2] * w.z + sh0[k + 3] * w.w;
    }
    sh1[c] = s2;
  }
  __syncthreads();
  {
    const float* wrow = W_mlp + 65536 + (size_t)c * 256;
    float s2 = b_mlp[256 + c];
#pragma unroll 8
    for (int k = 0; k < 256; k += 4) {
      float4 w = *(const float4*)&wrow[k];
      s2 += sh1[k] * w.x + sh1[k + 1] * w.y + sh1[k + 2] * w.z + sh1[k + 3] * w.w;
    }
    sh0[c] = s2;
  }
  __syncthreads();
  if (c < 2) {
    const float* wrow = W_fc + c * 256;
    float s2 = b_fc[c];
    for (int k = 0; k < 256; ++k) s2 += sh0[k] * wrow[k];
    outp[cry * 2 + c] = s2;
  }
}

extern "C" void kernel_launch(void* const* d_in, const int* in_sizes, int n_in,
                              void* d_out, int out_size, void* d_ws, size_t ws_size,
                              hipStream_t stream) {
  const float* bond  = (const float*)d_in[0];
  const float* angle = (const float*)d_in[1];
  const int*   nbr   = (const int*)d_in[3];
  const int*   crys  = (const int*)d_in[4];
  const float* Wl_b1 = (const float*)d_in[5];
  const float* Wr_b1 = (const float*)d_in[6];
  const float* b_b1  = (const float*)d_in[7];
  const float* Wl_a1 = (const float*)d_in[8];
  const float* Wr_a1 = (const float*)d_in[9];
  const float* b_a1  = (const float*)d_in[10];
  const float* Wl_b  = (const float*)d_in[11];
  const float* Wr_b  = (const float*)d_in[12];
  const float* b_b   = (const float*)d_in[13];
  const float* Wl_a  = (const float*)d_in[14];
  const float* Wr_a  = (const float*)d_in[15];
  const float* b_a   = (const float*)d_in[16];
  const float* W_mlp = (const float*)d_in[17];
  const float* b_mlp = (const float*)d_in[18];
  const float* W_fc  = (const float*)d_in[19];
  const float* b_fc  = (const float*)d_in[20];

  char* w = (char*)d_ws;
  auto alloc = [&](size_t bytes) {
    void* p = (void*)w;
    w += (bytes + 15) & ~(size_t)15;
    return p;
  };
  f16* P16    = (f16*)alloc((size_t)N_ATOMS * 128 * 2);
  f16* Q16    = (f16*)alloc((size_t)N_ATOMS * 128 * 2);
  f16* xb16   = (f16*)alloc((size_t)N_ATOMS * 128 * 2);
  f16* xa16   = (f16*)alloc((size_t)N_ATOMS * 128 * 2);
  f16* Wb1c   = (f16*)alloc((size_t)256 * 480 * 2);
  f16* Wa1c   = (f16*)alloc((size_t)256 * 1152 * 2);
  f16* Wsm    = (f16*)alloc((size_t)4 * 256 * 128 * 2);
  int* deg    = (int*)alloc((size_t)N_ATOMS * 4);
  int* cursor = (int*)alloc((size_t)N_ATOMS * 4);
  int* rowptr = (int*)alloc((size_t)(N_ATOMS + 1) * 4);
  int* eidx   = (int*)alloc((size_t)NEDGE * 4);
  int* bsum   = (int*)alloc(256 * 4);

  // ---- weights -> fp16 ----
  cvtW<<<dim3(2, 256), 256, 0, stream>>>(Wl_b1, Wr_b1, Wb1c, 480);
  cvtW<<<dim3(5, 256), 256, 0, stream>>>(Wl_a1, Wr_a1, Wa1c, 1152);
  cvtW_small<<<512, 256, 0, stream>>>(Wl_b, Wr_b, Wl_a, Wr_a, Wsm);

  // ---- CSR build (deg & cursor adjacent -> one memset) ----
  hipMemsetAsync(deg, 0, (size_t)2 * N_ATOMS * 4, stream);
  k_count<<<(NEDGE + 255) / 256, 256, 0, stream>>>(nbr, deg);
  k_scan1<<<NBLK, 256, 0, stream>>>(deg, rowptr, bsum);
  k_scan2<<<1, 256, 0, stream>>>(bsum);
  k_scan3<<<NBLK, 256, 0, stream>>>(rowptr, bsum);
  k_fill<<<(NEDGE + 255) / 256, 256, 0, stream>>>(nbr, rowptr, cursor, eidx);

  const int GG = (N_ATOMS + 127) / 128;  // 391
  const int AG = N_ATOMS / 16;           // 3125

  // ---- bond path ----
  gemm16<1, 480><<<GG, 512, 0, stream>>>(bond, Wb1c, P16, Q16, N_ATOMS);
  gather_fin<<<AG, 256, 0, stream>>>(P16, Q16, rowptr, eidx, b_b1, xb16);
  for (int l = 0; l < 2; ++l) {
    gemm16<0, 128><<<GG, 512, 0, stream>>>(xb16, Wsm + (size_t)l * 32768, P16, Q16, N_ATOMS);
    gather_fin<<<AG, 256, 0, stream>>>(P16, Q16, rowptr, eidx, b_b + l * 128, xb16);
  }

  // ---- angle path ----
  gemm16<2, 1152><<<GG, 512, 0, stream>>>(angle, Wa1c, P16, Q16, N_ATOMS);
  gather_fin<<<AG, 256, 0, stream>>>(P16, Q16, rowptr, eidx, b_a1, xa16);
  for (int l = 0; l < 2; ++l) {
    gemm16<0, 128><<<GG, 512, 0, stream>>>(xa16, Wsm + (size_t)(2 + l) * 32768, P16, Q16, N_ATOMS);
    gather_fin<<<AG, 256, 0, stream>>>(P16, Q16, rowptr, eidx, b_a + l * 128, xa16);
  }

  // ---- head ----
  head_kernel<<<NCRYS, 256, 0, stream>>>(xb16, xa16, crys, W_mlp, b_mlp, W_fc, b_fc,
                                         (float*)d_out);
}